// Round 7
// baseline (4740.533 us; speedup 1.0000x reference)
//
#include <hip/hip_runtime.h>
#include <hip/hip_bf16.h>
#include <math.h>

// Problem constants (match reference)
#define BB 4
#define PP 32768
#define TOPK 5000
#define NB 4096
#define NBK 20
#define TBPI 210         // NBK*(NBK+1)/2 triangular tile pairs
#define BMW 160          // bitmap words per row (157 used, 160 for 16B align)

// ws layout (bytes). Total 3,600,256 <= 3,742,720 proven available.
// Bitmap (suppressor-major, one image at a time) aliases dead phase-1 bufs.
#define NV_OFF     0u
#define NC_OFF     64u
#define CS_OFF     256u         // float[BB*TOPK]  = 80,000
#define CB_OFF     80256u       // float4[BB*TOPK] = 320,000 (ends 400,256)
#define HIST_OFF   400256u      // uint[BB*NB]
#define START_OFF  465792u      // uint[BB*NB]
#define CNT_OFF    531328u      // uint[BB*NB]
#define GIDX_OFF   596864u      // uint[BB*PP]
#define GSC_OFF    1121152u     // float[BB*PP] (ends 1,645,440)
#define BM_OFF     400256u      // uint[TOPK*BMW] = 3,200,000 (ends 3,600,256)
#define WS_NEEDED  3600256u

__global__ __launch_bounds__(256) void score_hist_kernel(
    const float2* __restrict__ conf, unsigned* __restrict__ hist)
{
    int i = blockIdx.x * 256 + threadIdx.x;
    if (i >= BB * PP) return;
    int b = i >> 15;
    float s = conf[i].y;
    if (s > 0.05f) {
        int bk = (int)(s * 4096.0f);
        bk = bk < 0 ? 0 : (bk > NB - 1 ? NB - 1 : bk);
        atomicAdd(&hist[b * NB + bk], 1u);
    }
}

__global__ __launch_bounds__(256) void scan_hist_kernel(
    const unsigned* __restrict__ hist, unsigned* __restrict__ start,
    int* __restrict__ nvalid, int* __restrict__ ncand)
{
    int b = blockIdx.x;
    int t = threadIdx.x;
    __shared__ unsigned sums[256];
    unsigned local[16];
    unsigned s = 0;
    const unsigned* hb = hist + b * NB;
    #pragma unroll
    for (int k = 0; k < 16; k++) {
        unsigned v = hb[t * 16 + k];
        local[k] = s;
        s += v;
    }
    sums[t] = s;
    __syncthreads();
    for (int off = 1; off < 256; off <<= 1) {
        unsigned v = (t >= off) ? sums[t - off] : 0u;
        __syncthreads();
        sums[t] += v;
        __syncthreads();
    }
    unsigned excl = sums[t] - s;
    unsigned* sb = start + b * NB;
    #pragma unroll
    for (int k = 0; k < 16; k++) sb[t * 16 + k] = excl + local[k];
    if (t == 255) {
        nvalid[b] = (int)sums[255];
        ncand[b] = sums[255] < (unsigned)TOPK ? (int)sums[255] : TOPK;
    }
}

__global__ __launch_bounds__(256) void scatter_group_kernel(
    const float2* __restrict__ conf, const unsigned* __restrict__ start,
    unsigned* __restrict__ cnt, unsigned* __restrict__ gidx,
    float* __restrict__ gscore)
{
    int i = blockIdx.x * 256 + threadIdx.x;
    if (i >= BB * PP) return;
    int b = i >> 15;
    int p = i & (PP - 1);
    float s = conf[i].y;
    if (s > 0.05f) {
        int bk = (int)(s * 4096.0f);
        bk = bk < 0 ? 0 : (bk > NB - 1 ? NB - 1 : bk);
        unsigned o = atomicAdd(&cnt[b * NB + bk], 1u);
        unsigned pos = start[b * NB + bk] + o;
        gidx[b * PP + pos] = (unsigned)p;
        gscore[b * PP + pos] = s;
    }
}

__global__ __launch_bounds__(256) void rank_topk_kernel(
    const unsigned* __restrict__ gidx, const float* __restrict__ gscore,
    const unsigned* __restrict__ start, const unsigned* __restrict__ hist,
    const int* __restrict__ nvalid, const float4* __restrict__ loc,
    const float4* __restrict__ prior,
    float* __restrict__ cs, float4* __restrict__ cb)
{
#pragma clang fp contract(off)
    int i = blockIdx.x * 256 + threadIdx.x;
    if (i >= BB * PP) return;
    int b = i >> 15;
    int pos = i & (PP - 1);
    int nv = nvalid[b];
    if (pos >= nv) return;
    float s = gscore[b * PP + pos];
    unsigned p = gidx[b * PP + pos];
    int bk = (int)(s * 4096.0f);
    bk = bk < 0 ? 0 : (bk > NB - 1 ? NB - 1 : bk);
    unsigned st = start[b * NB + bk];
    unsigned c = hist[b * NB + bk];
    unsigned rank = (unsigned)nv - st - c;
    const float* gs = gscore + b * PP + st;
    const unsigned* gi = gidx + b * PP + st;
    for (unsigned k = 0; k < c; k++) {
        float sk = gs[k];
        unsigned pk = gi[k];
        if (sk > s || (sk == s && pk < p)) rank++;
    }
    if (rank < (unsigned)TOPK) {
        float4 l = loc[b * PP + (int)p];
        float4 pr = prior[p];
        float cx = pr.x + (l.x * 0.1f) * pr.z;
        float cy = pr.y + (l.y * 0.1f) * pr.w;
        float w = pr.z * expf(l.z * 0.2f);
        float h = pr.w * expf(l.w * 0.2f);
        float4 bx;
        bx.x = cx - 0.5f * w;
        bx.y = cy - 0.5f * h;
        bx.z = cx + 0.5f * w;
        bx.w = cy + 0.5f * h;
        cs[b * TOPK + rank] = s;
        cb[(size_t)b * TOPK + rank] = bx;
    }
}

// Suppressor-major bitmap for ONE image: row j, bit i (i>j) set iff
// IoU(j,i) > 0.3 (exact reference fp ops; min/max/add commutative so the
// transposed evaluation is bitwise identical). Tile (bj=rows, bi=cols>=bj).
__global__ __launch_bounds__(256) void bitmap_pair_kernel(
    const float4* __restrict__ cb, int img, unsigned* __restrict__ bitmap)
{
#pragma clang fp contract(off)
    int t_ = blockIdx.x;
    int bi = (int)((sqrtf(8.0f * (float)t_ + 1.0f) - 1.0f) * 0.5f);
    while ((bi + 1) * (bi + 2) / 2 <= t_) bi++;
    while (bi * (bi + 1) / 2 > t_) bi--;
    int bj = t_ - bi * (bi + 1) / 2;   // bj <= bi: rows from bj, cols from bi

    const float4* cbb = cb + (size_t)img * TOPK;

    __shared__ float4 jb[256];
    __shared__ float ja[256];
    int tid = threadIdx.x;
    int cg = bi * 256 + tid;
    if (cg < TOPK) {
        float4 v = cbb[cg];
        jb[tid] = v;
        ja[tid] = (v.z - v.x) * (v.w - v.y);
    }
    __syncthreads();

    int r = bj * 256 + tid;
    if (r >= TOPK) return;
    float4 bx = cbb[r];
    float areaR = (bx.z - bx.x) * (bx.w - bx.y);
    bool diag = (bi == bj);

    unsigned wds[8];
    #pragma unroll
    for (int w8 = 0; w8 < 8; w8++) {
        unsigned m = 0u;
        int cb0 = w8 * 32;
        for (int k = 0; k < 32; k++) {
            int cl = cb0 + k;
            int c = bi * 256 + cl;
            if (c >= TOPK) break;
            if (diag && c <= r) continue;      // strict upper triangle
            float4 cc = jb[cl];
            float iw = fminf(bx.z, cc.z) - fmaxf(bx.x, cc.x);
            iw = fmaxf(iw, 0.0f);
            float ih = fminf(bx.w, cc.w) - fmaxf(bx.y, cc.y);
            ih = fmaxf(ih, 0.0f);
            float inter = iw * ih;
            float uni = (ja[cl] + areaR) - inter;  // area[i]+area[j]: commutative
            if (inter / uni > 0.3f) m |= (1u << k);
        }
        wds[w8] = m;
    }
    uint4* r4 = (uint4*)(bitmap + (size_t)r * BMW + bi * 8);
    r4[0] = make_uint4(wds[0], wds[1], wds[2], wds[3]);
    r4[1] = make_uint4(wds[4], wds[5], wds[6], wds[7]);
}

// One-wave serial greedy gather: for j in order, if not removed, kept;
// removed |= row[j]. R distributed: lane l owns words 4l..4l+3 (uint4).
// Rows register-prefetched 3 batches (48 rows) deep. Zero barriers in chain.
__global__ __launch_bounds__(64) void solve_gather_kernel(
    const float* __restrict__ cs, const float4* __restrict__ cb,
    const int* __restrict__ ncand, int img,
    const unsigned* __restrict__ bitmap, float* __restrict__ out)
{
    int lane = threadIdx.x;
    int nc = ncand[img];
    __shared__ unsigned kw[BMW];
    __shared__ unsigned pref[BMW];
    for (int w = lane; w < BMW; w += 64) kw[w] = 0u;
    __syncthreads();
    if (nc > 0) {
        unsigned R0, R1, R2, R3;
        {   // init: bits i >= nc are pre-removed
            unsigned m[4];
            #pragma unroll
            for (int q = 0; q < 4; q++) {
                int w = 4 * lane + q;
                int lo = w * 32;
                if (lo >= nc) m[q] = 0xffffffffu;
                else if (lo + 32 <= nc) m[q] = 0u;
                else m[q] = ~((1u << (nc - lo)) - 1u);
            }
            R0 = m[0]; R1 = m[1]; R2 = m[2]; R3 = m[3];
        }
        const unsigned* bm = bitmap;
        uint4 buf[3][16] = {};
        unsigned dia[3][16] = {};
        unsigned curW = 0u, keptW = 0u;

#define LOADB(S, BASE) do { \
    _Pragma("unroll") \
    for (int jj = 0; jj < 16; jj++) { \
        int j_ = (BASE) + jj; \
        if (j_ < nc) { \
            const unsigned* rp_ = bm + (size_t)j_ * BMW; \
            if (lane < 40) buf[S][jj] = *(const uint4*)(rp_ + 4 * lane); \
            dia[S][jj] = rp_[(unsigned)j_ >> 5]; \
        } \
    } \
} while (0)

#define PROCB(S, BASE) do { \
    _Pragma("unroll") \
    for (int jj = 0; jj < 16; jj++) { \
        int j_ = (BASE) + jj; \
        if (j_ < nc) { \
            if ((j_ & 31) == 0) { \
                unsigned w0_ = (unsigned)j_ >> 5; \
                unsigned q_ = w0_ & 3u; \
                unsigned Rs_ = (q_ == 0u) ? R0 : ((q_ == 1u) ? R1 : ((q_ == 2u) ? R2 : R3)); \
                curW = __shfl(Rs_, (int)(w0_ >> 2)); \
                if (j_ > 0) { if (lane == 0) kw[w0_ - 1] = keptW; keptW = 0u; } \
            } \
            if (((curW >> (j_ & 31)) & 1u) == 0u) { \
                unsigned w0_ = (unsigned)j_ >> 5; \
                uint4 v_ = buf[S][jj]; \
                unsigned wb_ = 4u * (unsigned)lane; \
                R0 |= (wb_ + 0u >= w0_) ? v_.x : 0u; \
                R1 |= (wb_ + 1u >= w0_) ? v_.y : 0u; \
                R2 |= (wb_ + 2u >= w0_) ? v_.z : 0u; \
                R3 |= (wb_ + 3u >= w0_) ? v_.w : 0u; \
                curW |= dia[S][jj]; \
                keptW |= (1u << (j_ & 31)); \
            } \
        } \
    } \
} while (0)

        LOADB(0, 0);
        LOADB(1, 16);
        for (int base = 0; base < nc; base += 48) {
            LOADB(2, base + 32); PROCB(0, base);
            LOADB(0, base + 48); PROCB(1, base + 16);
            LOADB(1, base + 64); PROCB(2, base + 32);
        }
        if (lane == 0) kw[(unsigned)(nc - 1) >> 5] = keptW;
#undef LOADB
#undef PROCB
    }
    __syncthreads();
    if (lane == 0) {
        unsigned s = 0;
        for (int w = 0; w < BMW; w++) { pref[w] = s; s += __popc(kw[w]); }
    }
    __syncthreads();

    const float* csb = cs + img * TOPK;
    const float4* cbb = cb + (size_t)img * TOPK;
    float* outb = out + ((size_t)img * 2 + 1) * TOPK * 5;
    for (int i = lane; i < nc; i += 64) {
        unsigned w = kw[i >> 5];
        if ((w >> (i & 31)) & 1u) {
            unsigned pos = pref[i >> 5] + __popc(w & ((1u << (i & 31)) - 1u));
            float4 bx = cbb[i];
            float* row = outb + (size_t)pos * 5;
            row[0] = csb[i];
            row[1] = bx.x;
            row[2] = bx.y;
            row[3] = bx.z;
            row[4] = bx.w;
        }
    }
}

extern "C" void kernel_launch(void* const* d_in, const int* in_sizes, int n_in,
                              void* d_out, int out_size, void* d_ws, size_t ws_size,
                              hipStream_t stream) {
    if (ws_size < WS_NEEDED) return;  // fail loudly rather than corrupt

    const float4* loc = (const float4*)d_in[0];
    const float2* conf = (const float2*)d_in[1];
    const float4* prior = (const float4*)d_in[2];
    float* out = (float*)d_out;

    char* ws = (char*)d_ws;
    int* nvalid = (int*)(ws + NV_OFF);
    int* ncand = (int*)(ws + NC_OFF);
    float* cs = (float*)(ws + CS_OFF);
    float4* cb = (float4*)(ws + CB_OFF);
    unsigned* hist = (unsigned*)(ws + HIST_OFF);
    unsigned* start = (unsigned*)(ws + START_OFF);
    unsigned* cnt = (unsigned*)(ws + CNT_OFF);
    unsigned* gidx = (unsigned*)(ws + GIDX_OFF);
    float* gscore = (float*)(ws + GSC_OFF);
    unsigned* bitmap = (unsigned*)(ws + BM_OFF);  // aliases dead phase-1 bufs

    hipMemsetAsync(d_out, 0, (size_t)out_size * sizeof(float), stream);
    hipMemsetAsync(hist, 0, (size_t)BB * NB * sizeof(unsigned), stream);
    hipMemsetAsync(cnt, 0, (size_t)BB * NB * sizeof(unsigned), stream);

    int nblk = (BB * PP + 255) / 256;
    score_hist_kernel<<<nblk, 256, 0, stream>>>(conf, hist);
    scan_hist_kernel<<<BB, 256, 0, stream>>>(hist, start, nvalid, ncand);
    scatter_group_kernel<<<nblk, 256, 0, stream>>>(conf, start, cnt, gidx, gscore);
    rank_topk_kernel<<<nblk, 256, 0, stream>>>(gidx, gscore, start, hist, nvalid,
                                               loc, prior, cs, cb);
    for (int b = 0; b < BB; b++) {
        bitmap_pair_kernel<<<TBPI, 256, 0, stream>>>(cb, b, bitmap);
        solve_gather_kernel<<<1, 64, 0, stream>>>(cs, cb, ncand, b, bitmap, out);
    }
}

// Round 8
// 2603.018 us; speedup vs baseline: 1.8212x; 1.8212x over previous
//
#include <hip/hip_runtime.h>
#include <hip/hip_bf16.h>
#include <math.h>

// Problem constants (match reference)
#define BB 4
#define PP 32768
#define TOPK 5000
#define NB 4096
#define NBK 20
#define TBPI 210         // NBK*(NBK+1)/2 triangular tile pairs
#define BMW 160          // bitmap words per row (157 used, 160 for 16B align)
#define SLOTW 256        // ring slot stride in words (1024B: full-wave DMA)

// ws layout (bytes). Total 3,600,256 <= 3,742,720 proven available.
// Bitmap (suppressor-major, one image at a time) aliases dead phase-1 bufs.
// NOTE: solve DMA reads up to 368B past bitmap end (lane padding) — still
// inside the proven ws region.
#define NV_OFF     0u
#define NC_OFF     64u
#define CS_OFF     256u         // float[BB*TOPK]  = 80,000
#define CB_OFF     80256u       // float4[BB*TOPK] = 320,000 (ends 400,256)
#define HIST_OFF   400256u      // uint[BB*NB]
#define START_OFF  465792u      // uint[BB*NB]
#define CNT_OFF    531328u      // uint[BB*NB]
#define GIDX_OFF   596864u      // uint[BB*PP]
#define GSC_OFF    1121152u     // float[BB*PP] (ends 1,645,440)
#define BM_OFF     400256u      // uint[TOPK*BMW] = 3,200,000 (ends 3,600,256)
#define WS_NEEDED  3600256u

__global__ __launch_bounds__(256) void score_hist_kernel(
    const float2* __restrict__ conf, unsigned* __restrict__ hist)
{
    int i = blockIdx.x * 256 + threadIdx.x;
    if (i >= BB * PP) return;
    int b = i >> 15;
    float s = conf[i].y;
    if (s > 0.05f) {
        int bk = (int)(s * 4096.0f);
        bk = bk < 0 ? 0 : (bk > NB - 1 ? NB - 1 : bk);
        atomicAdd(&hist[b * NB + bk], 1u);
    }
}

__global__ __launch_bounds__(256) void scan_hist_kernel(
    const unsigned* __restrict__ hist, unsigned* __restrict__ start,
    int* __restrict__ nvalid, int* __restrict__ ncand)
{
    int b = blockIdx.x;
    int t = threadIdx.x;
    __shared__ unsigned sums[256];
    unsigned local[16];
    unsigned s = 0;
    const unsigned* hb = hist + b * NB;
    #pragma unroll
    for (int k = 0; k < 16; k++) {
        unsigned v = hb[t * 16 + k];
        local[k] = s;
        s += v;
    }
    sums[t] = s;
    __syncthreads();
    for (int off = 1; off < 256; off <<= 1) {
        unsigned v = (t >= off) ? sums[t - off] : 0u;
        __syncthreads();
        sums[t] += v;
        __syncthreads();
    }
    unsigned excl = sums[t] - s;
    unsigned* sb = start + b * NB;
    #pragma unroll
    for (int k = 0; k < 16; k++) sb[t * 16 + k] = excl + local[k];
    if (t == 255) {
        nvalid[b] = (int)sums[255];
        ncand[b] = sums[255] < (unsigned)TOPK ? (int)sums[255] : TOPK;
    }
}

__global__ __launch_bounds__(256) void scatter_group_kernel(
    const float2* __restrict__ conf, const unsigned* __restrict__ start,
    unsigned* __restrict__ cnt, unsigned* __restrict__ gidx,
    float* __restrict__ gscore)
{
    int i = blockIdx.x * 256 + threadIdx.x;
    if (i >= BB * PP) return;
    int b = i >> 15;
    int p = i & (PP - 1);
    float s = conf[i].y;
    if (s > 0.05f) {
        int bk = (int)(s * 4096.0f);
        bk = bk < 0 ? 0 : (bk > NB - 1 ? NB - 1 : bk);
        unsigned o = atomicAdd(&cnt[b * NB + bk], 1u);
        unsigned pos = start[b * NB + bk] + o;
        gidx[b * PP + pos] = (unsigned)p;
        gscore[b * PP + pos] = s;
    }
}

__global__ __launch_bounds__(256) void rank_topk_kernel(
    const unsigned* __restrict__ gidx, const float* __restrict__ gscore,
    const unsigned* __restrict__ start, const unsigned* __restrict__ hist,
    const int* __restrict__ nvalid, const float4* __restrict__ loc,
    const float4* __restrict__ prior,
    float* __restrict__ cs, float4* __restrict__ cb)
{
#pragma clang fp contract(off)
    int i = blockIdx.x * 256 + threadIdx.x;
    if (i >= BB * PP) return;
    int b = i >> 15;
    int pos = i & (PP - 1);
    int nv = nvalid[b];
    if (pos >= nv) return;
    float s = gscore[b * PP + pos];
    unsigned p = gidx[b * PP + pos];
    int bk = (int)(s * 4096.0f);
    bk = bk < 0 ? 0 : (bk > NB - 1 ? NB - 1 : bk);
    unsigned st = start[b * NB + bk];
    unsigned c = hist[b * NB + bk];
    unsigned rank = (unsigned)nv - st - c;
    const float* gs = gscore + b * PP + st;
    const unsigned* gi = gidx + b * PP + st;
    for (unsigned k = 0; k < c; k++) {
        float sk = gs[k];
        unsigned pk = gi[k];
        if (sk > s || (sk == s && pk < p)) rank++;
    }
    if (rank < (unsigned)TOPK) {
        float4 l = loc[b * PP + (int)p];
        float4 pr = prior[p];
        float cx = pr.x + (l.x * 0.1f) * pr.z;
        float cy = pr.y + (l.y * 0.1f) * pr.w;
        float w = pr.z * expf(l.z * 0.2f);
        float h = pr.w * expf(l.w * 0.2f);
        float4 bx;
        bx.x = cx - 0.5f * w;
        bx.y = cy - 0.5f * h;
        bx.z = cx + 0.5f * w;
        bx.w = cy + 0.5f * h;
        cs[b * TOPK + rank] = s;
        cb[(size_t)b * TOPK + rank] = bx;
    }
}

// Suppressor-major bitmap for ONE image: row j, bit i (i>j) set iff
// IoU(j,i) > 0.3 (exact reference fp ops; min/max/add commutative so the
// transposed evaluation is bitwise identical). Proven absmax 0.0 (r7).
__global__ __launch_bounds__(256) void bitmap_pair_kernel(
    const float4* __restrict__ cb, int img, unsigned* __restrict__ bitmap)
{
#pragma clang fp contract(off)
    int t_ = blockIdx.x;
    int bi = (int)((sqrtf(8.0f * (float)t_ + 1.0f) - 1.0f) * 0.5f);
    while ((bi + 1) * (bi + 2) / 2 <= t_) bi++;
    while (bi * (bi + 1) / 2 > t_) bi--;
    int bj = t_ - bi * (bi + 1) / 2;   // bj <= bi: rows from bj, cols from bi

    const float4* cbb = cb + (size_t)img * TOPK;

    __shared__ float4 jb[256];
    __shared__ float ja[256];
    int tid = threadIdx.x;
    int cg = bi * 256 + tid;
    if (cg < TOPK) {
        float4 v = cbb[cg];
        jb[tid] = v;
        ja[tid] = (v.z - v.x) * (v.w - v.y);
    }
    __syncthreads();

    int r = bj * 256 + tid;
    if (r >= TOPK) return;
    float4 bx = cbb[r];
    float areaR = (bx.z - bx.x) * (bx.w - bx.y);
    bool diag = (bi == bj);

    unsigned wds[8];
    #pragma unroll
    for (int w8 = 0; w8 < 8; w8++) {
        unsigned m = 0u;
        int cb0 = w8 * 32;
        for (int k = 0; k < 32; k++) {
            int cl = cb0 + k;
            int c = bi * 256 + cl;
            if (c >= TOPK) break;
            if (diag && c <= r) continue;      // strict upper triangle
            float4 cc = jb[cl];
            float iw = fminf(bx.z, cc.z) - fmaxf(bx.x, cc.x);
            iw = fmaxf(iw, 0.0f);
            float ih = fminf(bx.w, cc.w) - fmaxf(bx.y, cc.y);
            ih = fmaxf(ih, 0.0f);
            float inter = iw * ih;
            float uni = (ja[cl] + areaR) - inter;  // area[i]+area[j]: commutative
            if (inter / uni > 0.3f) m |= (1u << k);
        }
        wds[w8] = m;
    }
    uint4* r4 = (uint4*)(bitmap + (size_t)r * BMW + bi * 8);
    r4[0] = make_uint4(wds[0], wds[1], wds[2], wds[3]);
    r4[1] = make_uint4(wds[4], wds[5], wds[6], wds[7]);
}

// One-wave serial greedy gather. Removed-mask R distributed: lane l owns
// words 4l..4l+3. Rows staged global->LDS by DMA (global_load_lds), 48 rows
// ahead, counted vmcnt(48): zero VGPR arrays, zero barriers in the chain.
__global__ __launch_bounds__(64) void solve_gather_kernel(
    const float* __restrict__ cs, const float4* __restrict__ cb,
    const int* __restrict__ ncand, int img,
    const unsigned* __restrict__ bitmap, float* __restrict__ out)
{
    int lane = threadIdx.x;
    int nc = ncand[img];
    __shared__ __align__(16) unsigned ring[64 * SLOTW];   // 64 KiB ring
    __shared__ unsigned kw[BMW];
    __shared__ unsigned pref[BMW];
    for (int w = lane; w < BMW; w += 64) kw[w] = 0u;
    __syncthreads();

    if (nc > 0) {
        unsigned R0, R1, R2, R3;
        {   // init removed-mask: bits i >= nc pre-removed
            unsigned m[4];
            #pragma unroll
            for (int q = 0; q < 4; q++) {
                int w = 4 * lane + q;
                int lo = w * 32;
                if (lo >= nc) m[q] = 0xffffffffu;
                else if (lo + 32 <= nc) m[q] = 0u;
                else m[q] = ~((1u << (nc - lo)) - 1u);
            }
            R0 = m[0]; R1 = m[1]; R2 = m[2]; R3 = m[3];
        }

        // DMA row J (640B payload; lanes 40-63 stage pad) into slot J&63.
        // Uniform guard => issued-DMA count is exactly min(16*(k+1), nc).
#define STAGE(J) do { \
    int j_ = (J); \
    if (j_ < nc) { \
        const unsigned* gp_ = bitmap + (size_t)j_ * BMW + (lane << 2); \
        unsigned* lp_ = &ring[(j_ & 63) << 8]; \
        __builtin_amdgcn_global_load_lds( \
            (const __attribute__((address_space(1))) unsigned*)gp_, \
            (__attribute__((address_space(3))) unsigned*)lp_, 16, 0, 0); \
    } \
} while (0)

        for (int j = 0; j < 48; ++j) STAGE(j);   // prologue: 3 batches

        unsigned curW = 0u, keptW = 0u;
        int nb = (nc + 15) >> 4;
        for (int k = 0; k < nb; ++k) {
            int b0 = k << 4;
            // stage batch k+3
            int sb = (k + 3) << 4;
            for (int jj = 0; jj < 16; ++jj) STAGE(sb + jj);
            // wait until batch k's 16 DMAs landed
            if (((k + 4) << 4) <= nc)
                asm volatile("s_waitcnt vmcnt(48)" ::: "memory");
            else
                asm volatile("s_waitcnt vmcnt(0)" ::: "memory");

            // word boundary (batches are 16, words 32: boundary iff b0%32==0)
            if ((b0 & 31) == 0) {
                if (b0 > 0 && lane == 0) kw[(b0 >> 5) - 1] = keptW;
                keptW = 0u;
                unsigned w0 = (unsigned)b0 >> 5;
                unsigned q = w0 & 3u;
                unsigned Rs = q == 0u ? R0 : q == 1u ? R1 : q == 2u ? R2 : R3;
                curW = __shfl(Rs, (int)(w0 >> 2));
            }

            // preload diagonal words (broadcast reads, off-chain)
            unsigned diaw[16];
            #pragma unroll
            for (int jj = 0; jj < 16; ++jj) {
                int j = b0 + jj;
                if (j < nc) diaw[jj] = ring[((j & 63) << 8) + (j >> 5)];
            }

            // serial chain: ds_read_b128 unconditional (pipelined), apply branchy
            #pragma unroll
            for (int jj = 0; jj < 16; ++jj) {
                int j = b0 + jj;
                if (j < nc) {
                    const uint4 v =
                        *(const uint4*)&ring[((j & 63) << 8) + (lane << 2)];
                    if (((curW >> (j & 31)) & 1u) == 0u) {   // j survives: kept
                        curW |= diaw[jj];
                        keptW |= 1u << (j & 31);
                        R0 |= v.x; R1 |= v.y; R2 |= v.z; R3 |= v.w;
                    }
                }
            }
        }
        if (lane == 0) kw[(unsigned)(nc - 1) >> 5] = keptW;
#undef STAGE
    }
    __syncthreads();
    if (lane == 0) {
        unsigned s = 0;
        for (int w = 0; w < BMW; w++) { pref[w] = s; s += __popc(kw[w]); }
    }
    __syncthreads();

    const float* csb = cs + img * TOPK;
    const float4* cbb = cb + (size_t)img * TOPK;
    float* outb = out + ((size_t)img * 2 + 1) * TOPK * 5;
    for (int i = lane; i < nc; i += 64) {
        unsigned w = kw[i >> 5];
        if ((w >> (i & 31)) & 1u) {
            unsigned pos = pref[i >> 5] + __popc(w & ((1u << (i & 31)) - 1u));
            float4 bx = cbb[i];
            float* row = outb + (size_t)pos * 5;
            row[0] = csb[i];
            row[1] = bx.x;
            row[2] = bx.y;
            row[3] = bx.z;
            row[4] = bx.w;
        }
    }
}

extern "C" void kernel_launch(void* const* d_in, const int* in_sizes, int n_in,
                              void* d_out, int out_size, void* d_ws, size_t ws_size,
                              hipStream_t stream) {
    if (ws_size < WS_NEEDED) return;  // fail loudly rather than corrupt

    const float4* loc = (const float4*)d_in[0];
    const float2* conf = (const float2*)d_in[1];
    const float4* prior = (const float4*)d_in[2];
    float* out = (float*)d_out;

    char* ws = (char*)d_ws;
    int* nvalid = (int*)(ws + NV_OFF);
    int* ncand = (int*)(ws + NC_OFF);
    float* cs = (float*)(ws + CS_OFF);
    float4* cb = (float4*)(ws + CB_OFF);
    unsigned* hist = (unsigned*)(ws + HIST_OFF);
    unsigned* start = (unsigned*)(ws + START_OFF);
    unsigned* cnt = (unsigned*)(ws + CNT_OFF);
    unsigned* gidx = (unsigned*)(ws + GIDX_OFF);
    float* gscore = (float*)(ws + GSC_OFF);
    unsigned* bitmap = (unsigned*)(ws + BM_OFF);  // aliases dead phase-1 bufs

    hipMemsetAsync(d_out, 0, (size_t)out_size * sizeof(float), stream);
    hipMemsetAsync(hist, 0, (size_t)BB * NB * sizeof(unsigned), stream);
    hipMemsetAsync(cnt, 0, (size_t)BB * NB * sizeof(unsigned), stream);

    int nblk = (BB * PP + 255) / 256;
    score_hist_kernel<<<nblk, 256, 0, stream>>>(conf, hist);
    scan_hist_kernel<<<BB, 256, 0, stream>>>(hist, start, nvalid, ncand);
    scatter_group_kernel<<<nblk, 256, 0, stream>>>(conf, start, cnt, gidx, gscore);
    rank_topk_kernel<<<nblk, 256, 0, stream>>>(gidx, gscore, start, hist, nvalid,
                                               loc, prior, cs, cb);
    for (int b = 0; b < BB; b++) {
        bitmap_pair_kernel<<<TBPI, 256, 0, stream>>>(cb, b, bitmap);
        solve_gather_kernel<<<1, 64, 0, stream>>>(cs, cb, ncand, b, bitmap, out);
    }
}

// Round 9
// 1893.400 us; speedup vs baseline: 2.5037x; 1.3748x over previous
//
#include <hip/hip_runtime.h>
#include <hip/hip_bf16.h>
#include <math.h>

// Problem constants (match reference)
#define BB 4
#define PP 32768
#define TOPK 5000
#define NB 4096
#define NBK 20
#define TBPI 210         // NBK*(NBK+1)/2 triangular tile pairs
#define BMW 160          // bitmap words per row (157 used, 160 for 16B align)
#define SLOTW 256        // ring slot stride in words (1024B: full-wave DMA)

// ws layout (bytes). Total 3,600,256 <= 3,742,720 proven available.
// Bitmap (suppressor-major, one image at a time) aliases dead phase-1 bufs.
#define NV_OFF     0u
#define NC_OFF     64u
#define CS_OFF     256u         // float[BB*TOPK]  = 80,000
#define CB_OFF     80256u       // float4[BB*TOPK] = 320,000 (ends 400,256)
#define HIST_OFF   400256u      // uint[BB*NB]
#define START_OFF  465792u      // uint[BB*NB]
#define CNT_OFF    531328u      // uint[BB*NB]
#define GIDX_OFF   596864u      // uint[BB*PP]
#define GSC_OFF    1121152u     // float[BB*PP] (ends 1,645,440)
#define BM_OFF     400256u      // uint[TOPK*BMW] = 3,200,000 (ends 3,600,256)
#define WS_NEEDED  3600256u

__global__ __launch_bounds__(256) void score_hist_kernel(
    const float2* __restrict__ conf, unsigned* __restrict__ hist)
{
    int i = blockIdx.x * 256 + threadIdx.x;
    if (i >= BB * PP) return;
    int b = i >> 15;
    float s = conf[i].y;
    if (s > 0.05f) {
        int bk = (int)(s * 4096.0f);
        bk = bk < 0 ? 0 : (bk > NB - 1 ? NB - 1 : bk);
        atomicAdd(&hist[b * NB + bk], 1u);
    }
}

__global__ __launch_bounds__(256) void scan_hist_kernel(
    const unsigned* __restrict__ hist, unsigned* __restrict__ start,
    int* __restrict__ nvalid, int* __restrict__ ncand)
{
    int b = blockIdx.x;
    int t = threadIdx.x;
    __shared__ unsigned sums[256];
    unsigned local[16];
    unsigned s = 0;
    const unsigned* hb = hist + b * NB;
    #pragma unroll
    for (int k = 0; k < 16; k++) {
        unsigned v = hb[t * 16 + k];
        local[k] = s;
        s += v;
    }
    sums[t] = s;
    __syncthreads();
    for (int off = 1; off < 256; off <<= 1) {
        unsigned v = (t >= off) ? sums[t - off] : 0u;
        __syncthreads();
        sums[t] += v;
        __syncthreads();
    }
    unsigned excl = sums[t] - s;
    unsigned* sb = start + b * NB;
    #pragma unroll
    for (int k = 0; k < 16; k++) sb[t * 16 + k] = excl + local[k];
    if (t == 255) {
        nvalid[b] = (int)sums[255];
        ncand[b] = sums[255] < (unsigned)TOPK ? (int)sums[255] : TOPK;
    }
}

__global__ __launch_bounds__(256) void scatter_group_kernel(
    const float2* __restrict__ conf, const unsigned* __restrict__ start,
    unsigned* __restrict__ cnt, unsigned* __restrict__ gidx,
    float* __restrict__ gscore)
{
    int i = blockIdx.x * 256 + threadIdx.x;
    if (i >= BB * PP) return;
    int b = i >> 15;
    int p = i & (PP - 1);
    float s = conf[i].y;
    if (s > 0.05f) {
        int bk = (int)(s * 4096.0f);
        bk = bk < 0 ? 0 : (bk > NB - 1 ? NB - 1 : bk);
        unsigned o = atomicAdd(&cnt[b * NB + bk], 1u);
        unsigned pos = start[b * NB + bk] + o;
        gidx[b * PP + pos] = (unsigned)p;
        gscore[b * PP + pos] = s;
    }
}

__global__ __launch_bounds__(256) void rank_topk_kernel(
    const unsigned* __restrict__ gidx, const float* __restrict__ gscore,
    const unsigned* __restrict__ start, const unsigned* __restrict__ hist,
    const int* __restrict__ nvalid, const float4* __restrict__ loc,
    const float4* __restrict__ prior,
    float* __restrict__ cs, float4* __restrict__ cb)
{
#pragma clang fp contract(off)
    int i = blockIdx.x * 256 + threadIdx.x;
    if (i >= BB * PP) return;
    int b = i >> 15;
    int pos = i & (PP - 1);
    int nv = nvalid[b];
    if (pos >= nv) return;
    float s = gscore[b * PP + pos];
    unsigned p = gidx[b * PP + pos];
    int bk = (int)(s * 4096.0f);
    bk = bk < 0 ? 0 : (bk > NB - 1 ? NB - 1 : bk);
    unsigned st = start[b * NB + bk];
    unsigned c = hist[b * NB + bk];
    unsigned rank = (unsigned)nv - st - c;
    const float* gs = gscore + b * PP + st;
    const unsigned* gi = gidx + b * PP + st;
    for (unsigned k = 0; k < c; k++) {
        float sk = gs[k];
        unsigned pk = gi[k];
        if (sk > s || (sk == s && pk < p)) rank++;
    }
    if (rank < (unsigned)TOPK) {
        float4 l = loc[b * PP + (int)p];
        float4 pr = prior[p];
        float cx = pr.x + (l.x * 0.1f) * pr.z;
        float cy = pr.y + (l.y * 0.1f) * pr.w;
        float w = pr.z * expf(l.z * 0.2f);
        float h = pr.w * expf(l.w * 0.2f);
        float4 bx;
        bx.x = cx - 0.5f * w;
        bx.y = cy - 0.5f * h;
        bx.z = cx + 0.5f * w;
        bx.w = cy + 0.5f * h;
        cs[b * TOPK + rank] = s;
        cb[(size_t)b * TOPK + rank] = bx;
    }
}

// Suppressor-major bitmap for ONE image: row j, bit i (i>j) set iff
// IoU(j,i) > 0.3 (exact reference fp ops). Proven absmax 0.0 (r7/r8).
__global__ __launch_bounds__(256) void bitmap_pair_kernel(
    const float4* __restrict__ cb, int img, unsigned* __restrict__ bitmap)
{
#pragma clang fp contract(off)
    int t_ = blockIdx.x;
    int bi = (int)((sqrtf(8.0f * (float)t_ + 1.0f) - 1.0f) * 0.5f);
    while ((bi + 1) * (bi + 2) / 2 <= t_) bi++;
    while (bi * (bi + 1) / 2 > t_) bi--;
    int bj = t_ - bi * (bi + 1) / 2;   // bj <= bi: rows from bj, cols from bi

    const float4* cbb = cb + (size_t)img * TOPK;

    __shared__ float4 jb[256];
    __shared__ float ja[256];
    int tid = threadIdx.x;
    int cg = bi * 256 + tid;
    if (cg < TOPK) {
        float4 v = cbb[cg];
        jb[tid] = v;
        ja[tid] = (v.z - v.x) * (v.w - v.y);
    }
    __syncthreads();

    int r = bj * 256 + tid;
    if (r >= TOPK) return;
    float4 bx = cbb[r];
    float areaR = (bx.z - bx.x) * (bx.w - bx.y);
    bool diag = (bi == bj);

    unsigned wds[8];
    #pragma unroll
    for (int w8 = 0; w8 < 8; w8++) {
        unsigned m = 0u;
        int cb0 = w8 * 32;
        for (int k = 0; k < 32; k++) {
            int cl = cb0 + k;
            int c = bi * 256 + cl;
            if (c >= TOPK) break;
            if (diag && c <= r) continue;      // strict upper triangle
            float4 cc = jb[cl];
            float iw = fminf(bx.z, cc.z) - fmaxf(bx.x, cc.x);
            iw = fmaxf(iw, 0.0f);
            float ih = fminf(bx.w, cc.w) - fmaxf(bx.y, cc.y);
            ih = fmaxf(ih, 0.0f);
            float inter = iw * ih;
            float uni = (ja[cl] + areaR) - inter;  // area[i]+area[j]: commutative
            if (inter / uni > 0.3f) m |= (1u << k);
        }
        wds[w8] = m;
    }
    uint4* r4 = (uint4*)(bitmap + (size_t)r * BMW + bi * 8);
    r4[0] = make_uint4(wds[0], wds[1], wds[2], wds[3]);
    r4[1] = make_uint4(wds[4], wds[5], wds[6], wds[7]);
}

// One-wave serial greedy gather, BRANCH-FREE chain. Removed-mask R distributed
// lane l owns words 4l..4l+3. Rows DMA-staged into a 64-slot LDS ring, 48 rows
// ahead (counted vmcnt(48)). Tail rows j>=nc self-mask: R init marks i>=nc
// removed, so alive=0 and all garbage reads are masked out.
__global__ __launch_bounds__(64) void solve_gather_kernel(
    const float* __restrict__ cs, const float4* __restrict__ cb,
    const int* __restrict__ ncand, int img,
    const unsigned* __restrict__ bitmap, float* __restrict__ out)
{
    int lane = threadIdx.x;
    int nc = ncand[img];
    __shared__ __align__(16) unsigned ring[64 * SLOTW];   // 64 KiB ring
    __shared__ unsigned kw[BMW];
    __shared__ unsigned pref[BMW];
    for (int w = lane; w < BMW; w += 64) kw[w] = 0u;
    __syncthreads();

    if (nc > 0) {
        unsigned R0, R1, R2, R3;
        {   // init removed-mask: bits i >= nc pre-removed
            unsigned m[4];
            #pragma unroll
            for (int q = 0; q < 4; q++) {
                int w = 4 * lane + q;
                int lo = w * 32;
                if (lo >= nc) m[q] = 0xffffffffu;
                else if (lo + 32 <= nc) m[q] = 0u;
                else m[q] = ~((1u << (nc - lo)) - 1u);
            }
            R0 = m[0]; R1 = m[1]; R2 = m[2]; R3 = m[3];
        }

#define STAGE(J) do { \
    int j_ = (J); \
    if (j_ < nc) { \
        const unsigned* gp_ = bitmap + (size_t)j_ * BMW + (lane << 2); \
        unsigned* lp_ = &ring[(j_ & 63) << 8]; \
        __builtin_amdgcn_global_load_lds( \
            (const __attribute__((address_space(1))) unsigned*)gp_, \
            (__attribute__((address_space(3))) unsigned*)lp_, 16, 0, 0); \
    } \
} while (0)

        for (int j = 0; j < 48; ++j) STAGE(j);   // prologue: 3 batches

        unsigned curW = 0u, keptW = 0u;
        int nb = (nc + 15) >> 4;
        for (int k = 0; k < nb; ++k) {
            int b0 = k << 4;
            int sb = (k + 3) << 4;
            for (int jj = 0; jj < 16; ++jj) STAGE(sb + jj);
            if (((k + 4) << 4) <= nc)
                asm volatile("s_waitcnt vmcnt(48)" ::: "memory");
            else
                asm volatile("s_waitcnt vmcnt(0)" ::: "memory");

            if ((b0 & 31) == 0) {    // word boundary (every other batch)
                if (b0 > 0 && lane == 0) kw[(b0 >> 5) - 1] = keptW;
                keptW = 0u;
                unsigned w0 = (unsigned)b0 >> 5;
                unsigned q = w0 & 3u;
                unsigned Rs = q == 0u ? R0 : q == 1u ? R1 : q == 2u ? R2 : R3;
                curW = __shfl(Rs, (int)(w0 >> 2));
            }

            // one straight-line block: all 32 LDS reads issue up front,
            // then a ~5-op/row serial VALU chain. No branches.
            unsigned diaw[16];
            #pragma unroll
            for (int jj = 0; jj < 16; ++jj) {
                int j = b0 + jj;
                diaw[jj] = ring[((j & 63) << 8) + ((unsigned)j >> 5)];
            }
            #pragma unroll
            for (int jj = 0; jj < 16; ++jj) {
                int j = b0 + jj;
                const uint4 v =
                    *(const uint4*)&ring[((j & 63) << 8) + (lane << 2)];
                unsigned alive = ((curW >> (j & 31)) & 1u) ^ 1u;  // 1 if kept
                unsigned msk = 0u - alive;
                curW |= diaw[jj] & msk;
                keptW |= alive << (j & 31);
                R0 |= v.x & msk;
                R1 |= v.y & msk;
                R2 |= v.z & msk;
                R3 |= v.w & msk;
            }
        }
        if (lane == 0) kw[(unsigned)(nc - 1) >> 5] = keptW;
#undef STAGE
    }
    __syncthreads();
    if (lane == 0) {
        unsigned s = 0;
        for (int w = 0; w < BMW; w++) { pref[w] = s; s += __popc(kw[w]); }
    }
    __syncthreads();

    const float* csb = cs + img * TOPK;
    const float4* cbb = cb + (size_t)img * TOPK;
    float* outb = out + ((size_t)img * 2 + 1) * TOPK * 5;
    for (int i = lane; i < nc; i += 64) {
        unsigned w = kw[i >> 5];
        if ((w >> (i & 31)) & 1u) {
            unsigned pos = pref[i >> 5] + __popc(w & ((1u << (i & 31)) - 1u));
            float4 bx = cbb[i];
            float* row = outb + (size_t)pos * 5;
            row[0] = csb[i];
            row[1] = bx.x;
            row[2] = bx.y;
            row[3] = bx.z;
            row[4] = bx.w;
        }
    }
}

extern "C" void kernel_launch(void* const* d_in, const int* in_sizes, int n_in,
                              void* d_out, int out_size, void* d_ws, size_t ws_size,
                              hipStream_t stream) {
    if (ws_size < WS_NEEDED) return;  // fail loudly rather than corrupt

    const float4* loc = (const float4*)d_in[0];
    const float2* conf = (const float2*)d_in[1];
    const float4* prior = (const float4*)d_in[2];
    float* out = (float*)d_out;

    char* ws = (char*)d_ws;
    int* nvalid = (int*)(ws + NV_OFF);
    int* ncand = (int*)(ws + NC_OFF);
    float* cs = (float*)(ws + CS_OFF);
    float4* cb = (float4*)(ws + CB_OFF);
    unsigned* hist = (unsigned*)(ws + HIST_OFF);
    unsigned* start = (unsigned*)(ws + START_OFF);
    unsigned* cnt = (unsigned*)(ws + CNT_OFF);
    unsigned* gidx = (unsigned*)(ws + GIDX_OFF);
    float* gscore = (float*)(ws + GSC_OFF);
    unsigned* bitmap = (unsigned*)(ws + BM_OFF);  // aliases dead phase-1 bufs

    hipMemsetAsync(d_out, 0, (size_t)out_size * sizeof(float), stream);
    hipMemsetAsync(hist, 0, (size_t)BB * NB * sizeof(unsigned), stream);
    hipMemsetAsync(cnt, 0, (size_t)BB * NB * sizeof(unsigned), stream);

    int nblk = (BB * PP + 255) / 256;
    score_hist_kernel<<<nblk, 256, 0, stream>>>(conf, hist);
    scan_hist_kernel<<<BB, 256, 0, stream>>>(hist, start, nvalid, ncand);
    scatter_group_kernel<<<nblk, 256, 0, stream>>>(conf, start, cnt, gidx, gscore);
    rank_topk_kernel<<<nblk, 256, 0, stream>>>(gidx, gscore, start, hist, nvalid,
                                               loc, prior, cs, cb);
    for (int b = 0; b < BB; b++) {
        bitmap_pair_kernel<<<TBPI, 256, 0, stream>>>(cb, b, bitmap);
        solve_gather_kernel<<<1, 64, 0, stream>>>(cs, cb, ncand, b, bitmap, out);
    }
}

// Round 10
// 741.875 us; speedup vs baseline: 6.3899x; 2.5522x over previous
//
#include <hip/hip_runtime.h>
#include <hip/hip_bf16.h>
#include <math.h>

// Problem constants (match reference)
#define BB 4
#define PP 32768
#define TOPK 5000
#define NB 4096
#define NBK 20
#define TBPI 210         // NBK*(NBK+1)/2 triangular tile pairs
#define BMW 160          // bitmap words per (full) row
#define SLOTW 256        // ring slot stride in words (1024B)
#define TRIW 411872u     // packed triangular bitmap words per image

// ws layout (bytes). End 3,695,232 (+ <1KB read overrun) <= 3,742,720 proven.
// TWO packed bitmaps alias the dead phase-1 buffers.
#define NV_OFF     0u
#define NC_OFF     64u
#define CS_OFF     256u         // float[BB*TOPK]  = 80,000
#define CB_OFF     80256u       // float4[BB*TOPK] = 320,000 (ends 400,256)
#define HIST_OFF   400256u      // uint[BB*NB]
#define START_OFF  465792u      // uint[BB*NB]
#define CNT_OFF    531328u      // uint[BB*NB]
#define GIDX_OFF   596864u      // uint[BB*PP]
#define GSC_OFF    1121152u     // float[BB*PP] (ends 1,645,440)
#define BM_OFF     400256u      // uint[2*TRIW] = 3,294,976 (ends 3,695,232)
#define WS_NEEDED  3742720u

// packed row start (words): toff(r) = 160r - 16q(q-1) - (r&31)q, q=r>>5.
// Row r stores words w in [q,160) at toff(r)+(w-q); rows are contiguous.
__device__ __forceinline__ unsigned toffw(unsigned r) {
    unsigned q = r >> 5, s = r & 31u;
    return r * 160u - 16u * q * (q - 1u) - s * q;
}

__global__ __launch_bounds__(256) void score_hist_kernel(
    const float2* __restrict__ conf, unsigned* __restrict__ hist)
{
    int i = blockIdx.x * 256 + threadIdx.x;
    if (i >= BB * PP) return;
    int b = i >> 15;
    float s = conf[i].y;
    if (s > 0.05f) {
        int bk = (int)(s * 4096.0f);
        bk = bk < 0 ? 0 : (bk > NB - 1 ? NB - 1 : bk);
        atomicAdd(&hist[b * NB + bk], 1u);
    }
}

__global__ __launch_bounds__(256) void scan_hist_kernel(
    const unsigned* __restrict__ hist, unsigned* __restrict__ start,
    int* __restrict__ nvalid, int* __restrict__ ncand)
{
    int b = blockIdx.x;
    int t = threadIdx.x;
    __shared__ unsigned sums[256];
    unsigned local[16];
    unsigned s = 0;
    const unsigned* hb = hist + b * NB;
    #pragma unroll
    for (int k = 0; k < 16; k++) {
        unsigned v = hb[t * 16 + k];
        local[k] = s;
        s += v;
    }
    sums[t] = s;
    __syncthreads();
    for (int off = 1; off < 256; off <<= 1) {
        unsigned v = (t >= off) ? sums[t - off] : 0u;
        __syncthreads();
        sums[t] += v;
        __syncthreads();
    }
    unsigned excl = sums[t] - s;
    unsigned* sb = start + b * NB;
    #pragma unroll
    for (int k = 0; k < 16; k++) sb[t * 16 + k] = excl + local[k];
    if (t == 255) {
        nvalid[b] = (int)sums[255];
        ncand[b] = sums[255] < (unsigned)TOPK ? (int)sums[255] : TOPK;
    }
}

__global__ __launch_bounds__(256) void scatter_group_kernel(
    const float2* __restrict__ conf, const unsigned* __restrict__ start,
    unsigned* __restrict__ cnt, unsigned* __restrict__ gidx,
    float* __restrict__ gscore)
{
    int i = blockIdx.x * 256 + threadIdx.x;
    if (i >= BB * PP) return;
    int b = i >> 15;
    int p = i & (PP - 1);
    float s = conf[i].y;
    if (s > 0.05f) {
        int bk = (int)(s * 4096.0f);
        bk = bk < 0 ? 0 : (bk > NB - 1 ? NB - 1 : bk);
        unsigned o = atomicAdd(&cnt[b * NB + bk], 1u);
        unsigned pos = start[b * NB + bk] + o;
        gidx[b * PP + pos] = (unsigned)p;
        gscore[b * PP + pos] = s;
    }
}

__global__ __launch_bounds__(256) void rank_topk_kernel(
    const unsigned* __restrict__ gidx, const float* __restrict__ gscore,
    const unsigned* __restrict__ start, const unsigned* __restrict__ hist,
    const int* __restrict__ nvalid, const float4* __restrict__ loc,
    const float4* __restrict__ prior,
    float* __restrict__ cs, float4* __restrict__ cb)
{
#pragma clang fp contract(off)
    int i = blockIdx.x * 256 + threadIdx.x;
    if (i >= BB * PP) return;
    int b = i >> 15;
    int pos = i & (PP - 1);
    int nv = nvalid[b];
    if (pos >= nv) return;
    float s = gscore[b * PP + pos];
    unsigned p = gidx[b * PP + pos];
    int bk = (int)(s * 4096.0f);
    bk = bk < 0 ? 0 : (bk > NB - 1 ? NB - 1 : bk);
    unsigned st = start[b * NB + bk];
    unsigned c = hist[b * NB + bk];
    unsigned rank = (unsigned)nv - st - c;
    const float* gs = gscore + b * PP + st;
    const unsigned* gi = gidx + b * PP + st;
    for (unsigned k = 0; k < c; k++) {
        float sk = gs[k];
        unsigned pk = gi[k];
        if (sk > s || (sk == s && pk < p)) rank++;
    }
    if (rank < (unsigned)TOPK) {
        float4 l = loc[b * PP + (int)p];
        float4 pr = prior[p];
        float cx = pr.x + (l.x * 0.1f) * pr.z;
        float cy = pr.y + (l.y * 0.1f) * pr.w;
        float w = pr.z * expf(l.z * 0.2f);
        float h = pr.w * expf(l.w * 0.2f);
        float4 bx;
        bx.x = cx - 0.5f * w;
        bx.y = cy - 0.5f * h;
        bx.z = cx + 0.5f * w;
        bx.w = cy + 0.5f * h;
        cs[b * TOPK + rank] = s;
        cb[(size_t)b * TOPK + rank] = bx;
    }
}

// Suppressor-major PACKED bitmap, two images per launch (p = blockIdx/TBPI).
// Row r: bit i (i>r) iff IoU(r,i)>0.3 — exact reference fp ops (proven r7-r9).
__global__ __launch_bounds__(256) void bitmap_pair_kernel(
    const float4* __restrict__ cb, int img_base, unsigned* __restrict__ bitmap)
{
#pragma clang fp contract(off)
    int p = blockIdx.x / TBPI;
    int t_ = blockIdx.x % TBPI;
    int img = img_base + p;
    unsigned* bmp = bitmap + (size_t)p * TRIW;

    int bi = (int)((sqrtf(8.0f * (float)t_ + 1.0f) - 1.0f) * 0.5f);
    while ((bi + 1) * (bi + 2) / 2 <= t_) bi++;
    while (bi * (bi + 1) / 2 > t_) bi--;
    int bj = t_ - bi * (bi + 1) / 2;   // bj <= bi: rows tile bj, cols tile bi

    const float4* cbb = cb + (size_t)img * TOPK;

    __shared__ float4 jb[256];
    __shared__ float ja[256];
    int tid = threadIdx.x;
    int cg = bi * 256 + tid;
    if (cg < TOPK) {
        float4 v = cbb[cg];
        jb[tid] = v;
        ja[tid] = (v.z - v.x) * (v.w - v.y);
    }
    __syncthreads();

    int r = bj * 256 + tid;
    if (r >= TOPK) return;
    float4 bx = cbb[r];
    float areaR = (bx.z - bx.x) * (bx.w - bx.y);
    bool diag = (bi == bj);

    unsigned wds[8];
    #pragma unroll
    for (int w8 = 0; w8 < 8; w8++) {
        unsigned m = 0u;
        int cb0 = w8 * 32;
        for (int k = 0; k < 32; k++) {
            int cl = cb0 + k;
            int c = bi * 256 + cl;
            if (c >= TOPK) break;
            if (diag && c <= r) continue;      // strict upper triangle
            float4 cc = jb[cl];
            float iw = fminf(bx.z, cc.z) - fmaxf(bx.x, cc.x);
            iw = fmaxf(iw, 0.0f);
            float ih = fminf(bx.w, cc.w) - fmaxf(bx.y, cc.y);
            ih = fmaxf(ih, 0.0f);
            float inter = iw * ih;
            float uni = (ja[cl] + areaR) - inter;
            if (inter / uni > 0.3f) m |= (1u << k);
        }
        wds[w8] = m;
    }
    unsigned q = (unsigned)r >> 5;
    unsigned basew = toffw((unsigned)r) - q + 8u * (unsigned)bi;
    int c0 = diag ? (int)(q - 8u * (unsigned)bj) : 0;  // first valid word
    for (int c = c0; c < 8; c++) bmp[basew + (unsigned)c] = wds[c];
}

// Producer/consumer solve: wave 0 = serial greedy chain (proven r9 logic),
// waves 1-2 = stagers (global_load_dword x4 -> ds_write_b128), depth-2 batch
// pipeline, barrier-lockstep per 16-row batch. grid = 2 images concurrent.
__global__ __launch_bounds__(192, 1) void solve_pc_kernel(
    const float* __restrict__ cs, const float4* __restrict__ cb,
    const int* __restrict__ ncand, int img_base,
    const unsigned* __restrict__ bitmap, float* __restrict__ out)
{
    int tid = threadIdx.x;
    int wv = tid >> 6;
    int lane = tid & 63;
    int img = img_base + blockIdx.x;
    int nc = ncand[img];
    const unsigned* bm = bitmap + (size_t)blockIdx.x * TRIW;

    __shared__ __align__(16) unsigned ring[64 * SLOTW];   // 64 KiB
    __shared__ unsigned kw[BMW];
    __shared__ unsigned pref[BMW];
    for (int w = tid; w < BMW; w += 192) kw[w] = 0u;

    int nb = (nc + 15) >> 4;
    int off8 = (wv - 1) * 8;          // producer rows: wave1 jj 0-7, wave2 8-15
    unsigned l4 = (unsigned)lane << 2;

    uint4 A[8], B[8];
    unsigned R0 = 0, R1 = 0, R2 = 0, R3 = 0;

    // load 8 rows of batch KB into BUF (4 dword loads/lane, packed addressing)
#define PL(BUF, KB) do {                                                   \
    int bq_ = (KB);                                                        \
    if (bq_ < nb) {                                                        \
        _Pragma("unroll")                                                  \
        for (int jj = 0; jj < 8; jj++) {                                   \
            int j_ = bq_ * 16 + jj + off8;                                 \
            if (j_ < nc) {                                                 \
                unsigned q_ = (unsigned)j_ >> 5;                           \
                const unsigned* p_ = bm + (toffw((unsigned)j_) - q_ + l4); \
                BUF[jj].x = p_[0]; BUF[jj].y = p_[1];                      \
                BUF[jj].z = p_[2]; BUF[jj].w = p_[3];                      \
            }                                                              \
        }                                                                  \
    }                                                                      \
} while (0)

#define PW(BUF, KB) do {                                                   \
    int bq_ = (KB);                                                        \
    if (bq_ < nb) {                                                        \
        _Pragma("unroll")                                                  \
        for (int jj = 0; jj < 8; jj++) {                                   \
            int j_ = bq_ * 16 + jj + off8;                                 \
            if (j_ < nc)                                                   \
                *(uint4*)&ring[(unsigned)((j_ & 63) << 8) + l4] = BUF[jj]; \
        }                                                                  \
    }                                                                      \
} while (0)

    if (wv == 0) {
        // consumer init: removed-mask, bits i >= nc pre-removed
        unsigned m[4];
        #pragma unroll
        for (int q = 0; q < 4; q++) {
            int w = 4 * lane + q;
            int lo = w * 32;
            if (lo >= nc) m[q] = 0xffffffffu;
            else if (lo + 32 <= nc) m[q] = 0u;
            else m[q] = ~((1u << (nc - lo)) - 1u);
        }
        R0 = m[0]; R1 = m[1]; R2 = m[2]; R3 = m[3];
    } else {
        PL(A, 0);
        PW(A, 0);      // batch 0 staged (vmcnt handled by compiler)
        PL(B, 1);
        PL(A, 2);
    }
    __syncthreads();   // batch 0 ready

    unsigned curW = 0u, keptW = 0u;
    for (int k = 0; k < nb; ++k) {
        if (wv == 0) {
            int b0 = k << 4;
            if ((b0 & 31) == 0) {        // word boundary
                if (b0 > 0 && lane == 0) kw[(b0 >> 5) - 1] = keptW;
                keptW = 0u;
                unsigned w0 = (unsigned)b0 >> 5;
                unsigned q = w0 & 3u;
                unsigned Rs = q == 0u ? R0 : q == 1u ? R1 : q == 2u ? R2 : R3;
                curW = __shfl(Rs, (int)(w0 >> 2));
            }
            unsigned diaw[16];
            #pragma unroll
            for (int jj = 0; jj < 16; ++jj) {
                int j = b0 + jj;
                diaw[jj] = ring[(unsigned)((j & 63) << 8) + ((unsigned)j >> 5)];
            }
            #pragma unroll
            for (int jj = 0; jj < 16; ++jj) {
                int j = b0 + jj;
                const uint4 v =
                    *(const uint4*)&ring[(unsigned)((j & 63) << 8) + l4];
                unsigned alive = ((curW >> (j & 31)) & 1u) ^ 1u;
                unsigned msk = 0u - alive;
                curW |= diaw[jj] & msk;
                keptW |= alive << (j & 31);
                R0 |= v.x & msk;
                R1 |= v.y & msk;
                R2 |= v.z & msk;
                R3 |= v.w & msk;
            }
        } else {
            if ((k & 1) == 0) { PW(B, k + 1); PL(B, k + 3); }
            else              { PW(A, k + 1); PL(A, k + 3); }
        }
        __syncthreads();
    }
#undef PL
#undef PW
    if (wv == 0 && nc > 0 && lane == 0) kw[(unsigned)(nc - 1) >> 5] = keptW;
    __syncthreads();
    if (tid == 0) {
        unsigned s = 0;
        for (int w = 0; w < BMW; w++) { pref[w] = s; s += __popc(kw[w]); }
    }
    __syncthreads();

    const float* csb = cs + img * TOPK;
    const float4* cbb = cb + (size_t)img * TOPK;
    float* outb = out + ((size_t)img * 2 + 1) * TOPK * 5;
    for (int i = tid; i < nc; i += 192) {
        unsigned w = kw[i >> 5];
        if ((w >> (i & 31)) & 1u) {
            unsigned pos = pref[i >> 5] + __popc(w & ((1u << (i & 31)) - 1u));
            float4 bx = cbb[i];
            float* row = outb + (size_t)pos * 5;
            row[0] = csb[i];
            row[1] = bx.x;
            row[2] = bx.y;
            row[3] = bx.z;
            row[4] = bx.w;
        }
    }
}

extern "C" void kernel_launch(void* const* d_in, const int* in_sizes, int n_in,
                              void* d_out, int out_size, void* d_ws, size_t ws_size,
                              hipStream_t stream) {
    if (ws_size < WS_NEEDED) return;  // fail loudly rather than corrupt

    const float4* loc = (const float4*)d_in[0];
    const float2* conf = (const float2*)d_in[1];
    const float4* prior = (const float4*)d_in[2];
    float* out = (float*)d_out;

    char* ws = (char*)d_ws;
    int* nvalid = (int*)(ws + NV_OFF);
    int* ncand = (int*)(ws + NC_OFF);
    float* cs = (float*)(ws + CS_OFF);
    float4* cb = (float4*)(ws + CB_OFF);
    unsigned* hist = (unsigned*)(ws + HIST_OFF);
    unsigned* start = (unsigned*)(ws + START_OFF);
    unsigned* cnt = (unsigned*)(ws + CNT_OFF);
    unsigned* gidx = (unsigned*)(ws + GIDX_OFF);
    float* gscore = (float*)(ws + GSC_OFF);
    unsigned* bitmap = (unsigned*)(ws + BM_OFF);  // 2 packed images

    hipMemsetAsync(d_out, 0, (size_t)out_size * sizeof(float), stream);
    hipMemsetAsync(hist, 0, (size_t)BB * NB * sizeof(unsigned), stream);
    hipMemsetAsync(cnt, 0, (size_t)BB * NB * sizeof(unsigned), stream);

    int nblk = (BB * PP + 255) / 256;
    score_hist_kernel<<<nblk, 256, 0, stream>>>(conf, hist);
    scan_hist_kernel<<<BB, 256, 0, stream>>>(hist, start, nvalid, ncand);
    scatter_group_kernel<<<nblk, 256, 0, stream>>>(conf, start, cnt, gidx, gscore);
    rank_topk_kernel<<<nblk, 256, 0, stream>>>(gidx, gscore, start, hist, nvalid,
                                               loc, prior, cs, cb);
    for (int g = 0; g < 2; ++g) {
        bitmap_pair_kernel<<<2 * TBPI, 256, 0, stream>>>(cb, 2 * g, bitmap);
        solve_pc_kernel<<<2, 192, 0, stream>>>(cs, cb, ncand, 2 * g, bitmap, out);
    }
}

// Round 11
// 738.664 us; speedup vs baseline: 6.4177x; 1.0043x over previous
//
#include <hip/hip_runtime.h>
#include <hip/hip_bf16.h>
#include <math.h>

// Problem constants (match reference)
#define BB 4
#define PP 32768
#define TOPK 5000
#define NB 4096
#define NBK 20
#define TBPI 210         // NBK*(NBK+1)/2 triangular tile pairs
#define BMW 160          // bitmap words per (full) row
#define SLOTW 256        // ring slot stride in words (1024B)
#define TRIW 411872u     // packed triangular bitmap words per image

// ws layout (bytes). End 3,695,232 <= 3,742,720 proven available.
// TWO packed bitmaps alias the dead phase-1 buffers.
#define NV_OFF     0u
#define NC_OFF     64u
#define CS_OFF     256u         // float[BB*TOPK]  = 80,000
#define CB_OFF     80256u       // float4[BB*TOPK] = 320,000 (ends 400,256)
#define HIST_OFF   400256u      // uint[BB*NB]
#define START_OFF  465792u      // uint[BB*NB]
#define CNT_OFF    531328u      // uint[BB*NB]
#define GIDX_OFF   596864u      // uint[BB*PP]
#define GSC_OFF    1121152u     // float[BB*PP] (ends 1,645,440)
#define BM_OFF     400256u      // uint[2*TRIW] = 3,294,976 (ends 3,695,232)
#define WS_NEEDED  3742720u

// packed row start (words): toff(r) = 160r - 16q(q-1) - (r&31)q, q=r>>5.
__device__ __forceinline__ unsigned toffw(unsigned r) {
    unsigned q = r >> 5, s = r & 31u;
    return r * 160u - 16u * q * (q - 1u) - s * q;
}

__global__ __launch_bounds__(256) void score_hist_kernel(
    const float2* __restrict__ conf, unsigned* __restrict__ hist)
{
    int i = blockIdx.x * 256 + threadIdx.x;
    if (i >= BB * PP) return;
    int b = i >> 15;
    float s = conf[i].y;
    if (s > 0.05f) {
        int bk = (int)(s * 4096.0f);
        bk = bk < 0 ? 0 : (bk > NB - 1 ? NB - 1 : bk);
        atomicAdd(&hist[b * NB + bk], 1u);
    }
}

__global__ __launch_bounds__(256) void scan_hist_kernel(
    const unsigned* __restrict__ hist, unsigned* __restrict__ start,
    int* __restrict__ nvalid, int* __restrict__ ncand)
{
    int b = blockIdx.x;
    int t = threadIdx.x;
    __shared__ unsigned sums[256];
    unsigned local[16];
    unsigned s = 0;
    const unsigned* hb = hist + b * NB;
    #pragma unroll
    for (int k = 0; k < 16; k++) {
        unsigned v = hb[t * 16 + k];
        local[k] = s;
        s += v;
    }
    sums[t] = s;
    __syncthreads();
    for (int off = 1; off < 256; off <<= 1) {
        unsigned v = (t >= off) ? sums[t - off] : 0u;
        __syncthreads();
        sums[t] += v;
        __syncthreads();
    }
    unsigned excl = sums[t] - s;
    unsigned* sb = start + b * NB;
    #pragma unroll
    for (int k = 0; k < 16; k++) sb[t * 16 + k] = excl + local[k];
    if (t == 255) {
        nvalid[b] = (int)sums[255];
        ncand[b] = sums[255] < (unsigned)TOPK ? (int)sums[255] : TOPK;
    }
}

__global__ __launch_bounds__(256) void scatter_group_kernel(
    const float2* __restrict__ conf, const unsigned* __restrict__ start,
    unsigned* __restrict__ cnt, unsigned* __restrict__ gidx,
    float* __restrict__ gscore)
{
    int i = blockIdx.x * 256 + threadIdx.x;
    if (i >= BB * PP) return;
    int b = i >> 15;
    int p = i & (PP - 1);
    float s = conf[i].y;
    if (s > 0.05f) {
        int bk = (int)(s * 4096.0f);
        bk = bk < 0 ? 0 : (bk > NB - 1 ? NB - 1 : bk);
        unsigned o = atomicAdd(&cnt[b * NB + bk], 1u);
        unsigned pos = start[b * NB + bk] + o;
        gidx[b * PP + pos] = (unsigned)p;
        gscore[b * PP + pos] = s;
    }
}

__global__ __launch_bounds__(256) void rank_topk_kernel(
    const unsigned* __restrict__ gidx, const float* __restrict__ gscore,
    const unsigned* __restrict__ start, const unsigned* __restrict__ hist,
    const int* __restrict__ nvalid, const float4* __restrict__ loc,
    const float4* __restrict__ prior,
    float* __restrict__ cs, float4* __restrict__ cb)
{
#pragma clang fp contract(off)
    int i = blockIdx.x * 256 + threadIdx.x;
    if (i >= BB * PP) return;
    int b = i >> 15;
    int pos = i & (PP - 1);
    int nv = nvalid[b];
    if (pos >= nv) return;
    float s = gscore[b * PP + pos];
    unsigned p = gidx[b * PP + pos];
    int bk = (int)(s * 4096.0f);
    bk = bk < 0 ? 0 : (bk > NB - 1 ? NB - 1 : bk);
    unsigned st = start[b * NB + bk];
    unsigned c = hist[b * NB + bk];
    unsigned rank = (unsigned)nv - st - c;
    const float* gs = gscore + b * PP + st;
    const unsigned* gi = gidx + b * PP + st;
    for (unsigned k = 0; k < c; k++) {
        float sk = gs[k];
        unsigned pk = gi[k];
        if (sk > s || (sk == s && pk < p)) rank++;
    }
    if (rank < (unsigned)TOPK) {
        float4 l = loc[b * PP + (int)p];
        float4 pr = prior[p];
        float cx = pr.x + (l.x * 0.1f) * pr.z;
        float cy = pr.y + (l.y * 0.1f) * pr.w;
        float w = pr.z * expf(l.z * 0.2f);
        float h = pr.w * expf(l.w * 0.2f);
        float4 bx;
        bx.x = cx - 0.5f * w;
        bx.y = cy - 0.5f * h;
        bx.z = cx + 0.5f * w;
        bx.w = cy + 0.5f * h;
        cs[b * TOPK + rank] = s;
        cb[(size_t)b * TOPK + rank] = bx;
    }
}

// Suppressor-major PACKED bitmap, two images per launch (p = blockIdx/TBPI).
// Row r: bit i (i>r) iff IoU(r,i)>0.3 — exact reference fp ops (proven r7-r10).
__global__ __launch_bounds__(256) void bitmap_pair_kernel(
    const float4* __restrict__ cb, int img_base, unsigned* __restrict__ bitmap)
{
#pragma clang fp contract(off)
    int p = blockIdx.x / TBPI;
    int t_ = blockIdx.x % TBPI;
    int img = img_base + p;
    unsigned* bmp = bitmap + (size_t)p * TRIW;

    int bi = (int)((sqrtf(8.0f * (float)t_ + 1.0f) - 1.0f) * 0.5f);
    while ((bi + 1) * (bi + 2) / 2 <= t_) bi++;
    while (bi * (bi + 1) / 2 > t_) bi--;
    int bj = t_ - bi * (bi + 1) / 2;

    const float4* cbb = cb + (size_t)img * TOPK;

    __shared__ float4 jb[256];
    __shared__ float ja[256];
    int tid = threadIdx.x;
    int cg = bi * 256 + tid;
    if (cg < TOPK) {
        float4 v = cbb[cg];
        jb[tid] = v;
        ja[tid] = (v.z - v.x) * (v.w - v.y);
    }
    __syncthreads();

    int r = bj * 256 + tid;
    if (r >= TOPK) return;
    float4 bx = cbb[r];
    float areaR = (bx.z - bx.x) * (bx.w - bx.y);
    bool diag = (bi == bj);

    unsigned wds[8];
    #pragma unroll
    for (int w8 = 0; w8 < 8; w8++) {
        unsigned m = 0u;
        int cb0 = w8 * 32;
        for (int k = 0; k < 32; k++) {
            int cl = cb0 + k;
            int c = bi * 256 + cl;
            if (c >= TOPK) break;
            if (diag && c <= r) continue;      // strict upper triangle
            float4 cc = jb[cl];
            float iw = fminf(bx.z, cc.z) - fmaxf(bx.x, cc.x);
            iw = fmaxf(iw, 0.0f);
            float ih = fminf(bx.w, cc.w) - fmaxf(bx.y, cc.y);
            ih = fmaxf(ih, 0.0f);
            float inter = iw * ih;
            float uni = (ja[cl] + areaR) - inter;
            if (inter / uni > 0.3f) m |= (1u << k);
        }
        wds[w8] = m;
    }
    unsigned q = (unsigned)r >> 5;
    unsigned basew = toffw((unsigned)r) - q + 8u * (unsigned)bi;
    int c0 = diag ? (int)(q - 8u * (unsigned)bj) : 0;
    for (int c = c0; c < 8; c++) bmp[basew + (unsigned)c] = wds[c];
}

// Producer/consumer solve. Consumer batch = {load vv[16]+diaw[16] to regs,
// sched_barrier, pure-VALU chain} so LDS latency is paid once per batch,
// not per row. Producers: depth-2 batch pipeline (proven r10).
__global__ __launch_bounds__(192, 1) void solve_pc_kernel(
    const float* __restrict__ cs, const float4* __restrict__ cb,
    const int* __restrict__ ncand, int img_base,
    const unsigned* __restrict__ bitmap, float* __restrict__ out)
{
    int tid = threadIdx.x;
    int wv = tid >> 6;
    int lane = tid & 63;
    int img = img_base + blockIdx.x;
    int nc = ncand[img];
    const unsigned* bm = bitmap + (size_t)blockIdx.x * TRIW;

    __shared__ __align__(16) unsigned ring[64 * SLOTW];   // 64 KiB
    __shared__ unsigned kw[BMW];
    __shared__ unsigned pref[BMW];
    for (int w = tid; w < BMW; w += 192) kw[w] = 0u;

    int nb = (nc + 15) >> 4;
    int off8 = (wv - 1) * 8;          // producer rows: wave1 jj 0-7, wave2 8-15
    unsigned l4 = (unsigned)lane << 2;

    uint4 A[8], B[8];
    unsigned R0 = 0, R1 = 0, R2 = 0, R3 = 0;

#define PL(BUF, KB) do {                                                   \
    int bq_ = (KB);                                                        \
    if (bq_ < nb) {                                                        \
        _Pragma("unroll")                                                  \
        for (int jj = 0; jj < 8; jj++) {                                   \
            int j_ = bq_ * 16 + jj + off8;                                 \
            if (j_ < nc) {                                                 \
                unsigned q_ = (unsigned)j_ >> 5;                           \
                const unsigned* p_ = bm + (toffw((unsigned)j_) - q_ + l4); \
                BUF[jj].x = p_[0]; BUF[jj].y = p_[1];                      \
                BUF[jj].z = p_[2]; BUF[jj].w = p_[3];                      \
            }                                                              \
        }                                                                  \
    }                                                                      \
} while (0)

#define PW(BUF, KB) do {                                                   \
    int bq_ = (KB);                                                        \
    if (bq_ < nb) {                                                        \
        _Pragma("unroll")                                                  \
        for (int jj = 0; jj < 8; jj++) {                                   \
            int j_ = bq_ * 16 + jj + off8;                                 \
            if (j_ < nc)                                                   \
                *(uint4*)&ring[(unsigned)((j_ & 63) << 8) + l4] = BUF[jj]; \
        }                                                                  \
    }                                                                      \
} while (0)

    if (wv == 0) {
        unsigned m[4];
        #pragma unroll
        for (int q = 0; q < 4; q++) {
            int w = 4 * lane + q;
            int lo = w * 32;
            if (lo >= nc) m[q] = 0xffffffffu;
            else if (lo + 32 <= nc) m[q] = 0u;
            else m[q] = ~((1u << (nc - lo)) - 1u);
        }
        R0 = m[0]; R1 = m[1]; R2 = m[2]; R3 = m[3];
    } else {
        PL(A, 0);
        PW(A, 0);
        PL(B, 1);
        PL(A, 2);
    }
    __syncthreads();   // batch 0 ready

    unsigned curW = 0u, keptW = 0u;
    for (int k = 0; k < nb; ++k) {
        if (wv == 0) {
            int b0 = k << 4;
            if ((b0 & 31) == 0) {        // word boundary
                if (b0 > 0 && lane == 0) kw[(b0 >> 5) - 1] = keptW;
                keptW = 0u;
                unsigned w0 = (unsigned)b0 >> 5;
                unsigned q = w0 & 3u;
                unsigned Rs = q == 0u ? R0 : q == 1u ? R1 : q == 2u ? R2 : R3;
                curW = __shfl(Rs, (int)(w0 >> 2));
            }
            // ---- load phase: all 32 LDS reads into registers (static idx) ----
            unsigned diaw[16];
            uint4 vv[16];
            #pragma unroll
            for (int jj = 0; jj < 16; ++jj) {
                int j = b0 + jj;
                unsigned slot = (unsigned)((j & 63) << 8);
                diaw[jj] = ring[slot + ((unsigned)j >> 5)];
                vv[jj] = *(const uint4*)&ring[slot + l4];
            }
            __builtin_amdgcn_sched_barrier(0);   // pin loads above the chain
            // ---- pure-VALU serial chain ----
            #pragma unroll
            for (int jj = 0; jj < 16; ++jj) {
                int j = b0 + jj;
                unsigned alive = ((curW >> (j & 31)) & 1u) ^ 1u;
                unsigned msk = 0u - alive;
                curW |= diaw[jj] & msk;
                keptW |= alive << (j & 31);
                R0 |= vv[jj].x & msk;
                R1 |= vv[jj].y & msk;
                R2 |= vv[jj].z & msk;
                R3 |= vv[jj].w & msk;
            }
        } else {
            if ((k & 1) == 0) { PW(B, k + 1); PL(B, k + 3); }
            else              { PW(A, k + 1); PL(A, k + 3); }
        }
        __syncthreads();
    }
#undef PL
#undef PW
    if (wv == 0 && nc > 0 && lane == 0) kw[(unsigned)(nc - 1) >> 5] = keptW;
    __syncthreads();
    if (tid == 0) {
        unsigned s = 0;
        for (int w = 0; w < BMW; w++) { pref[w] = s; s += __popc(kw[w]); }
    }
    __syncthreads();

    const float* csb = cs + img * TOPK;
    const float4* cbb = cb + (size_t)img * TOPK;
    float* outb = out + ((size_t)img * 2 + 1) * TOPK * 5;
    for (int i = tid; i < nc; i += 192) {
        unsigned w = kw[i >> 5];
        if ((w >> (i & 31)) & 1u) {
            unsigned pos = pref[i >> 5] + __popc(w & ((1u << (i & 31)) - 1u));
            float4 bx = cbb[i];
            float* row = outb + (size_t)pos * 5;
            row[0] = csb[i];
            row[1] = bx.x;
            row[2] = bx.y;
            row[3] = bx.z;
            row[4] = bx.w;
        }
    }
}

extern "C" void kernel_launch(void* const* d_in, const int* in_sizes, int n_in,
                              void* d_out, int out_size, void* d_ws, size_t ws_size,
                              hipStream_t stream) {
    if (ws_size < WS_NEEDED) return;  // fail loudly rather than corrupt

    const float4* loc = (const float4*)d_in[0];
    const float2* conf = (const float2*)d_in[1];
    const float4* prior = (const float4*)d_in[2];
    float* out = (float*)d_out;

    char* ws = (char*)d_ws;
    int* nvalid = (int*)(ws + NV_OFF);
    int* ncand = (int*)(ws + NC_OFF);
    float* cs = (float*)(ws + CS_OFF);
    float4* cb = (float4*)(ws + CB_OFF);
    unsigned* hist = (unsigned*)(ws + HIST_OFF);
    unsigned* start = (unsigned*)(ws + START_OFF);
    unsigned* cnt = (unsigned*)(ws + CNT_OFF);
    unsigned* gidx = (unsigned*)(ws + GIDX_OFF);
    float* gscore = (float*)(ws + GSC_OFF);
    unsigned* bitmap = (unsigned*)(ws + BM_OFF);  // 2 packed images

    hipMemsetAsync(d_out, 0, (size_t)out_size * sizeof(float), stream);
    hipMemsetAsync(hist, 0, (size_t)BB * NB * sizeof(unsigned), stream);
    hipMemsetAsync(cnt, 0, (size_t)BB * NB * sizeof(unsigned), stream);

    int nblk = (BB * PP + 255) / 256;
    score_hist_kernel<<<nblk, 256, 0, stream>>>(conf, hist);
    scan_hist_kernel<<<BB, 256, 0, stream>>>(hist, start, nvalid, ncand);
    scatter_group_kernel<<<nblk, 256, 0, stream>>>(conf, start, cnt, gidx, gscore);
    rank_topk_kernel<<<nblk, 256, 0, stream>>>(gidx, gscore, start, hist, nvalid,
                                               loc, prior, cs, cb);
    for (int g = 0; g < 2; ++g) {
        bitmap_pair_kernel<<<2 * TBPI, 256, 0, stream>>>(cb, 2 * g, bitmap);
        solve_pc_kernel<<<2, 192, 0, stream>>>(cs, cb, ncand, 2 * g, bitmap, out);
    }
}

// Round 12
// 738.513 us; speedup vs baseline: 6.4190x; 1.0002x over previous
//
#include <hip/hip_runtime.h>
#include <hip/hip_bf16.h>
#include <math.h>

// Problem constants (match reference)
#define BB 4
#define PP 32768
#define TOPK 5000
#define NB 4096
#define NBK 20
#define TBPI 210         // NBK*(NBK+1)/2 triangular tile pairs
#define BMW 160          // bitmap words per (full) row
#define SLOTW 256        // ring slot stride in words (1024B)
#define TRIW 411872u     // packed triangular bitmap words per image

// ws layout (bytes). End 3,695,232 <= 3,742,720 proven available.
// TWO packed bitmaps alias the dead phase-1 buffers.
#define NV_OFF     0u
#define NC_OFF     64u
#define CS_OFF     256u         // float[BB*TOPK]  = 80,000
#define CB_OFF     80256u       // float4[BB*TOPK] = 320,000 (ends 400,256)
#define HIST_OFF   400256u      // uint[BB*NB]
#define START_OFF  465792u      // uint[BB*NB]
#define CNT_OFF    531328u      // uint[BB*NB]
#define GIDX_OFF   596864u      // uint[BB*PP]
#define GSC_OFF    1121152u     // float[BB*PP] (ends 1,645,440)
#define BM_OFF     400256u      // uint[2*TRIW] = 3,294,976 (ends 3,695,232)
#define WS_NEEDED  3742720u

// packed row start (words): toff(r) = 160r - 16q(q-1) - (r&31)q, q=r>>5.
__device__ __forceinline__ unsigned toffw(unsigned r) {
    unsigned q = r >> 5, s = r & 31u;
    return r * 160u - 16u * q * (q - 1u) - s * q;
}

__global__ __launch_bounds__(256) void score_hist_kernel(
    const float2* __restrict__ conf, unsigned* __restrict__ hist)
{
    int i = blockIdx.x * 256 + threadIdx.x;
    if (i >= BB * PP) return;
    int b = i >> 15;
    float s = conf[i].y;
    if (s > 0.05f) {
        int bk = (int)(s * 4096.0f);
        bk = bk < 0 ? 0 : (bk > NB - 1 ? NB - 1 : bk);
        atomicAdd(&hist[b * NB + bk], 1u);
    }
}

__global__ __launch_bounds__(256) void scan_hist_kernel(
    const unsigned* __restrict__ hist, unsigned* __restrict__ start,
    int* __restrict__ nvalid, int* __restrict__ ncand)
{
    int b = blockIdx.x;
    int t = threadIdx.x;
    __shared__ unsigned sums[256];
    unsigned local[16];
    unsigned s = 0;
    const unsigned* hb = hist + b * NB;
    #pragma unroll
    for (int k = 0; k < 16; k++) {
        unsigned v = hb[t * 16 + k];
        local[k] = s;
        s += v;
    }
    sums[t] = s;
    __syncthreads();
    for (int off = 1; off < 256; off <<= 1) {
        unsigned v = (t >= off) ? sums[t - off] : 0u;
        __syncthreads();
        sums[t] += v;
        __syncthreads();
    }
    unsigned excl = sums[t] - s;
    unsigned* sb = start + b * NB;
    #pragma unroll
    for (int k = 0; k < 16; k++) sb[t * 16 + k] = excl + local[k];
    if (t == 255) {
        nvalid[b] = (int)sums[255];
        ncand[b] = sums[255] < (unsigned)TOPK ? (int)sums[255] : TOPK;
    }
}

__global__ __launch_bounds__(256) void scatter_group_kernel(
    const float2* __restrict__ conf, const unsigned* __restrict__ start,
    unsigned* __restrict__ cnt, unsigned* __restrict__ gidx,
    float* __restrict__ gscore)
{
    int i = blockIdx.x * 256 + threadIdx.x;
    if (i >= BB * PP) return;
    int b = i >> 15;
    int p = i & (PP - 1);
    float s = conf[i].y;
    if (s > 0.05f) {
        int bk = (int)(s * 4096.0f);
        bk = bk < 0 ? 0 : (bk > NB - 1 ? NB - 1 : bk);
        unsigned o = atomicAdd(&cnt[b * NB + bk], 1u);
        unsigned pos = start[b * NB + bk] + o;
        gidx[b * PP + pos] = (unsigned)p;
        gscore[b * PP + pos] = s;
    }
}

__global__ __launch_bounds__(256) void rank_topk_kernel(
    const unsigned* __restrict__ gidx, const float* __restrict__ gscore,
    const unsigned* __restrict__ start, const unsigned* __restrict__ hist,
    const int* __restrict__ nvalid, const float4* __restrict__ loc,
    const float4* __restrict__ prior,
    float* __restrict__ cs, float4* __restrict__ cb)
{
#pragma clang fp contract(off)
    int i = blockIdx.x * 256 + threadIdx.x;
    if (i >= BB * PP) return;
    int b = i >> 15;
    int pos = i & (PP - 1);
    int nv = nvalid[b];
    if (pos >= nv) return;
    float s = gscore[b * PP + pos];
    unsigned p = gidx[b * PP + pos];
    int bk = (int)(s * 4096.0f);
    bk = bk < 0 ? 0 : (bk > NB - 1 ? NB - 1 : bk);
    unsigned st = start[b * NB + bk];
    unsigned c = hist[b * NB + bk];
    unsigned rank = (unsigned)nv - st - c;
    const float* gs = gscore + b * PP + st;
    const unsigned* gi = gidx + b * PP + st;
    for (unsigned k = 0; k < c; k++) {
        float sk = gs[k];
        unsigned pk = gi[k];
        if (sk > s || (sk == s && pk < p)) rank++;
    }
    if (rank < (unsigned)TOPK) {
        float4 l = loc[b * PP + (int)p];
        float4 pr = prior[p];
        float cx = pr.x + (l.x * 0.1f) * pr.z;
        float cy = pr.y + (l.y * 0.1f) * pr.w;
        float w = pr.z * expf(l.z * 0.2f);
        float h = pr.w * expf(l.w * 0.2f);
        float4 bx;
        bx.x = cx - 0.5f * w;
        bx.y = cy - 0.5f * h;
        bx.z = cx + 0.5f * w;
        bx.w = cy + 0.5f * h;
        cs[b * TOPK + rank] = s;
        cb[(size_t)b * TOPK + rank] = bx;
    }
}

// Suppressor-major PACKED bitmap, two images per launch (p = blockIdx/TBPI).
// Row r: bit i (i>r) iff IoU(r,i)>0.3 — exact reference fp ops (proven r7-r11).
__global__ __launch_bounds__(256) void bitmap_pair_kernel(
    const float4* __restrict__ cb, int img_base, unsigned* __restrict__ bitmap)
{
#pragma clang fp contract(off)
    int p = blockIdx.x / TBPI;
    int t_ = blockIdx.x % TBPI;
    int img = img_base + p;
    unsigned* bmp = bitmap + (size_t)p * TRIW;

    int bi = (int)((sqrtf(8.0f * (float)t_ + 1.0f) - 1.0f) * 0.5f);
    while ((bi + 1) * (bi + 2) / 2 <= t_) bi++;
    while (bi * (bi + 1) / 2 > t_) bi--;
    int bj = t_ - bi * (bi + 1) / 2;

    const float4* cbb = cb + (size_t)img * TOPK;

    __shared__ float4 jb[256];
    __shared__ float ja[256];
    int tid = threadIdx.x;
    int cg = bi * 256 + tid;
    if (cg < TOPK) {
        float4 v = cbb[cg];
        jb[tid] = v;
        ja[tid] = (v.z - v.x) * (v.w - v.y);
    }
    __syncthreads();

    int r = bj * 256 + tid;
    if (r >= TOPK) return;
    float4 bx = cbb[r];
    float areaR = (bx.z - bx.x) * (bx.w - bx.y);
    bool diag = (bi == bj);

    unsigned wds[8];
    #pragma unroll
    for (int w8 = 0; w8 < 8; w8++) {
        unsigned m = 0u;
        int cb0 = w8 * 32;
        for (int k = 0; k < 32; k++) {
            int cl = cb0 + k;
            int c = bi * 256 + cl;
            if (c >= TOPK) break;
            if (diag && c <= r) continue;      // strict upper triangle
            float4 cc = jb[cl];
            float iw = fminf(bx.z, cc.z) - fmaxf(bx.x, cc.x);
            iw = fmaxf(iw, 0.0f);
            float ih = fminf(bx.w, cc.w) - fmaxf(bx.y, cc.y);
            ih = fmaxf(ih, 0.0f);
            float inter = iw * ih;
            float uni = (ja[cl] + areaR) - inter;
            if (inter / uni > 0.3f) m |= (1u << k);
        }
        wds[w8] = m;
    }
    unsigned q = (unsigned)r >> 5;
    unsigned basew = toffw((unsigned)r) - q + 8u * (unsigned)bi;
    int c0 = diag ? (int)(q - 8u * (unsigned)bj) : 0;
    for (int c = c0; c < 8; c++) bmp[basew + (unsigned)c] = wds[c];
}

// Producer/consumer solve. In-loop barrier is RAW s_barrier + lgkmcnt(0) only
// (no vmcnt drain) so the producers' depth-2 global-load pipeline survives the
// barrier; the compiler's scoreboard inserts exact counted vmcnt waits before
// the ds_writes that consume loaded registers.
__global__ __launch_bounds__(192, 1) void solve_pc_kernel(
    const float* __restrict__ cs, const float4* __restrict__ cb,
    const int* __restrict__ ncand, int img_base,
    const unsigned* __restrict__ bitmap, float* __restrict__ out)
{
    int tid = threadIdx.x;
    int wv = tid >> 6;
    int lane = tid & 63;
    int img = img_base + blockIdx.x;
    int nc = ncand[img];
    const unsigned* bm = bitmap + (size_t)blockIdx.x * TRIW;

    __shared__ __align__(16) unsigned ring[64 * SLOTW];   // 64 KiB
    __shared__ unsigned kw[BMW];
    __shared__ unsigned pref[BMW];
    for (int w = tid; w < BMW; w += 192) kw[w] = 0u;

    int nb = (nc + 15) >> 4;
    int off8 = (wv - 1) * 8;          // producer rows: wave1 jj 0-7, wave2 8-15
    unsigned l4 = (unsigned)lane << 2;

    uint4 A[8], B[8];
    unsigned R0 = 0, R1 = 0, R2 = 0, R3 = 0;

#define PL(BUF, KB) do {                                                   \
    int bq_ = (KB);                                                        \
    if (bq_ < nb) {                                                        \
        _Pragma("unroll")                                                  \
        for (int jj = 0; jj < 8; jj++) {                                   \
            int j_ = bq_ * 16 + jj + off8;                                 \
            if (j_ < nc) {                                                 \
                unsigned q_ = (unsigned)j_ >> 5;                           \
                const unsigned* p_ = bm + (toffw((unsigned)j_) - q_ + l4); \
                BUF[jj].x = p_[0]; BUF[jj].y = p_[1];                      \
                BUF[jj].z = p_[2]; BUF[jj].w = p_[3];                      \
            }                                                              \
        }                                                                  \
    }                                                                      \
} while (0)

#define PW(BUF, KB) do {                                                   \
    int bq_ = (KB);                                                        \
    if (bq_ < nb) {                                                        \
        _Pragma("unroll")                                                  \
        for (int jj = 0; jj < 8; jj++) {                                   \
            int j_ = bq_ * 16 + jj + off8;                                 \
            if (j_ < nc)                                                   \
                *(uint4*)&ring[(unsigned)((j_ & 63) << 8) + l4] = BUF[jj]; \
        }                                                                  \
    }                                                                      \
} while (0)

    if (wv == 0) {
        unsigned m[4];
        #pragma unroll
        for (int q = 0; q < 4; q++) {
            int w = 4 * lane + q;
            int lo = w * 32;
            if (lo >= nc) m[q] = 0xffffffffu;
            else if (lo + 32 <= nc) m[q] = 0u;
            else m[q] = ~((1u << (nc - lo)) - 1u);
        }
        R0 = m[0]; R1 = m[1]; R2 = m[2]; R3 = m[3];
    } else {
        PL(A, 0);
        PW(A, 0);
        PL(B, 1);
        PL(A, 2);
    }
    __syncthreads();   // batch 0 ready (one-time full drain is fine)

    unsigned curW = 0u, keptW = 0u;
    for (int k = 0; k < nb; ++k) {
        if (wv == 0) {
            int b0 = k << 4;
            if ((b0 & 31) == 0) {        // word boundary
                if (b0 > 0 && lane == 0) kw[(b0 >> 5) - 1] = keptW;
                keptW = 0u;
                unsigned w0 = (unsigned)b0 >> 5;
                unsigned q = w0 & 3u;
                unsigned Rs = q == 0u ? R0 : q == 1u ? R1 : q == 2u ? R2 : R3;
                curW = __shfl(Rs, (int)(w0 >> 2));
            }
            // load phase: all LDS reads into registers (static indices)
            unsigned diaw[16];
            uint4 vv[16];
            #pragma unroll
            for (int jj = 0; jj < 16; ++jj) {
                int j = b0 + jj;
                unsigned slot = (unsigned)((j & 63) << 8);
                diaw[jj] = ring[slot + ((unsigned)j >> 5)];
                vv[jj] = *(const uint4*)&ring[slot + l4];
            }
            __builtin_amdgcn_sched_barrier(0);
            // pure-VALU serial chain
            #pragma unroll
            for (int jj = 0; jj < 16; ++jj) {
                int j = b0 + jj;
                unsigned alive = ((curW >> (j & 31)) & 1u) ^ 1u;
                unsigned msk = 0u - alive;
                curW |= diaw[jj] & msk;
                keptW |= alive << (j & 31);
                R0 |= vv[jj].x & msk;
                R1 |= vv[jj].y & msk;
                R2 |= vv[jj].z & msk;
                R3 |= vv[jj].w & msk;
            }
        } else {
            if ((k & 1) == 0) { PW(B, k + 1); PL(B, k + 3); }
            else              { PW(A, k + 1); PL(A, k + 3); }
        }
        // RAW barrier: LDS ordering only, NO vmcnt drain (keeps prefetch alive)
        asm volatile("s_waitcnt lgkmcnt(0)" ::: "memory");
        __builtin_amdgcn_s_barrier();
    }
#undef PL
#undef PW
    if (wv == 0 && nc > 0 && lane == 0) kw[(unsigned)(nc - 1) >> 5] = keptW;
    __syncthreads();
    if (tid == 0) {
        unsigned s = 0;
        for (int w = 0; w < BMW; w++) { pref[w] = s; s += __popc(kw[w]); }
    }
    __syncthreads();

    const float* csb = cs + img * TOPK;
    const float4* cbb = cb + (size_t)img * TOPK;
    float* outb = out + ((size_t)img * 2 + 1) * TOPK * 5;
    for (int i = tid; i < nc; i += 192) {
        unsigned w = kw[i >> 5];
        if ((w >> (i & 31)) & 1u) {
            unsigned pos = pref[i >> 5] + __popc(w & ((1u << (i & 31)) - 1u));
            float4 bx = cbb[i];
            float* row = outb + (size_t)pos * 5;
            row[0] = csb[i];
            row[1] = bx.x;
            row[2] = bx.y;
            row[3] = bx.z;
            row[4] = bx.w;
        }
    }
}

extern "C" void kernel_launch(void* const* d_in, const int* in_sizes, int n_in,
                              void* d_out, int out_size, void* d_ws, size_t ws_size,
                              hipStream_t stream) {
    if (ws_size < WS_NEEDED) return;  // fail loudly rather than corrupt

    const float4* loc = (const float4*)d_in[0];
    const float2* conf = (const float2*)d_in[1];
    const float4* prior = (const float4*)d_in[2];
    float* out = (float*)d_out;

    char* ws = (char*)d_ws;
    int* nvalid = (int*)(ws + NV_OFF);
    int* ncand = (int*)(ws + NC_OFF);
    float* cs = (float*)(ws + CS_OFF);
    float4* cb = (float4*)(ws + CB_OFF);
    unsigned* hist = (unsigned*)(ws + HIST_OFF);
    unsigned* start = (unsigned*)(ws + START_OFF);
    unsigned* cnt = (unsigned*)(ws + CNT_OFF);
    unsigned* gidx = (unsigned*)(ws + GIDX_OFF);
    float* gscore = (float*)(ws + GSC_OFF);
    unsigned* bitmap = (unsigned*)(ws + BM_OFF);  // 2 packed images

    hipMemsetAsync(d_out, 0, (size_t)out_size * sizeof(float), stream);
    hipMemsetAsync(hist, 0, (size_t)BB * NB * sizeof(unsigned), stream);
    hipMemsetAsync(cnt, 0, (size_t)BB * NB * sizeof(unsigned), stream);

    int nblk = (BB * PP + 255) / 256;
    score_hist_kernel<<<nblk, 256, 0, stream>>>(conf, hist);
    scan_hist_kernel<<<BB, 256, 0, stream>>>(hist, start, nvalid, ncand);
    scatter_group_kernel<<<nblk, 256, 0, stream>>>(conf, start, cnt, gidx, gscore);
    rank_topk_kernel<<<nblk, 256, 0, stream>>>(gidx, gscore, start, hist, nvalid,
                                               loc, prior, cs, cb);
    for (int g = 0; g < 2; ++g) {
        bitmap_pair_kernel<<<2 * TBPI, 256, 0, stream>>>(cb, 2 * g, bitmap);
        solve_pc_kernel<<<2, 192, 0, stream>>>(cs, cb, ncand, 2 * g, bitmap, out);
    }
}